// Round 18
// baseline (147.968 us; speedup 1.0000x reference)
//
#include <hip/hip_runtime.h>

#define BN 8192      // B*N
#define NP 1024      // N
#define NF 64        // F_OUT
#define NSEG 8192
#define NBIN 1024    // bins of 8 segments (bin = seg >> 3)
#define CAPBIN 1184  // Poisson(1024) + 5 sigma; overflow exact
#define OVF_MAX 4096
#define OVFS (1 << 30)   // sentinel: cursor values >= OVFS index the ovf list

typedef float f32x4 __attribute__((ext_vector_type(4)));

// K1: blocks [0,nsb): block-local counting sort of 8192 edges into dense global
//     per-bin strips. blocks [nsb,..): dual MLP, 16 rows/block.
__global__ __launch_bounds__(1024) void prep_kernel(
    const float* __restrict__ x,
    const float* __restrict__ W1, const float* __restrict__ b1,
    const float* __restrict__ W2, const float* __restrict__ b2,
    const float* __restrict__ Ws1, const float* __restrict__ bs1,
    const float* __restrict__ Ws2, const float* __restrict__ bs2,
    const int* __restrict__ eb, const int* __restrict__ ei,
    const int* __restrict__ ej, const int* __restrict__ ek,
    int* __restrict__ gcur, int2* __restrict__ rec,
    int* __restrict__ ovf_cnt, int4* __restrict__ ovf,
    float* __restrict__ x1, float* __restrict__ out,
    int nnz, int nsb)
{
    if ((int)blockIdx.x < nsb) {
        __shared__ int hist[NBIN];
        __shared__ int cur[NBIN];
        const int t = threadIdx.x;
        hist[t] = 0;
        __syncthreads();

        int segs[8], jks[8];
        const int base = blockIdx.x * 8192;
        #pragma unroll
        for (int q = 0; q < 2; ++q) {
            const int e0 = base + (q * 1024 + t) * 4;
            if (e0 < nnz) {
                const int4 b4 = *(const int4*)(eb + e0);
                const int4 i4 = *(const int4*)(ei + e0);
                const int4 j4 = *(const int4*)(ej + e0);
                const int4 k4 = *(const int4*)(ek + e0);
                segs[q*4+0] = b4.x * NP + i4.x;  jks[q*4+0] = (j4.x << 10) | k4.x;
                segs[q*4+1] = b4.y * NP + i4.y;  jks[q*4+1] = (j4.y << 10) | k4.y;
                segs[q*4+2] = b4.z * NP + i4.z;  jks[q*4+2] = (j4.z << 10) | k4.z;
                segs[q*4+3] = b4.w * NP + i4.w;  jks[q*4+3] = (j4.w << 10) | k4.w;
                #pragma unroll
                for (int c = 0; c < 4; ++c)
                    atomicAdd(&hist[segs[q*4+c] >> 3], 1);
            } else {
                #pragma unroll
                for (int c = 0; c < 4; ++c) segs[q*4+c] = -1;
            }
        }
        __syncthreads();

        {
            const int v = hist[t];
            int c = 0;
            if (v > 0) {
                const int r = atomicAdd(&gcur[t], v);
                if (r + v <= CAPBIN) {
                    c = t * CAPBIN + r;
                } else {
                    atomicSub(&gcur[t], v);
                    c = OVFS + atomicAdd(ovf_cnt, v);
                }
            }
            cur[t] = c;
        }
        __syncthreads();

        #pragma unroll
        for (int q = 0; q < 2; ++q) {
            #pragma unroll
            for (int c = 0; c < 4; ++c) {
                const int idx = q * 4 + c;
                if (segs[idx] >= 0) {
                    const int e = base + (q * 1024 + t) * 4 + c;
                    const int seg = segs[idx];
                    const int p = atomicAdd(&cur[seg >> 3], 1);   // LDS atomic
                    if (p < OVFS) {
                        rec[p] = make_int2(e | ((seg & 7) << 20), jks[idx]);
                    } else {
                        const int o = p - OVFS;
                        if (o < OVF_MAX) ovf[o] = make_int4(seg, e, jks[idx], 0);
                    }
                }
            }
        }
    } else {
        const int row = ((int)blockIdx.x - nsb) * 16 + ((int)threadIdx.x >> 6);
        const int t = threadIdx.x & 63;
        const float xv = x[(size_t)row * NF + t];
        float a1 = b1[t], a2 = bs1[t];
        #pragma unroll 8
        for (int c = 0; c < NF; ++c) {
            const float xc = __shfl(xv, c);
            a1 = fmaf(xc, W1[c * NF + t], a1);
            a2 = fmaf(xc, Ws1[c * NF + t], a2);
        }
        const float h1 = fmaxf(a1, 0.f), h2 = fmaxf(a2, 0.f);
        float o1 = b2[t], o2 = bs2[t];
        #pragma unroll 8
        for (int c = 0; c < NF; ++c) {
            o1 = fmaf(__shfl(h1, c), W2[c * NF + t], o1);
            o2 = fmaf(__shfl(h2, c), Ws2[c * NF + t], o2);
        }
        x1[(size_t)row * NF + t]  = fmaxf(o1, 0.f);
        out[(size_t)row * NF + t] = fmaxf(o2, 0.f);
    }
}

// K2: block per bin (512 thr = 8 waves), as in round 17.
__global__ __launch_bounds__(512, 8) void gather_kernel(
    const f32x4* __restrict__ Wv4, const f32x4* __restrict__ x14,
    const int* __restrict__ gcur, const int2* __restrict__ rec,
    const int* __restrict__ ovf_cnt, const int4* __restrict__ ovf,
    f32x4* __restrict__ out4)
{
    __shared__ int2 srt[CAPBIN];
    __shared__ int hist[8], cur2[8], base2[8];
    const int bin = blockIdx.x;
    const int t = threadIdx.x;
    const int cnt = gcur[bin];
    if (t < 8) hist[t] = 0;
    __syncthreads();

    const int2* strip = rec + (size_t)bin * CAPBIN;
    #pragma unroll
    for (int i = 0; i < 3; ++i) {
        const int idx = i * 512 + t;
        if (idx < cnt) atomicAdd(&hist[(strip[idx].x >> 20) & 7], 1);
    }
    __syncthreads();
    if (t < 8) {
        int bsum = 0;
        for (int s = 0; s < t; ++s) bsum += hist[s];
        base2[t] = bsum; cur2[t] = bsum;
    }
    __syncthreads();
    #pragma unroll
    for (int i = 0; i < 3; ++i) {
        const int idx = i * 512 + t;
        if (idx < cnt) {
            const int2 r = strip[idx];
            srt[atomicAdd(&cur2[(r.x >> 20) & 7], 1)] = r;
        }
    }
    __syncthreads();

    const int w    = t >> 6;
    const int lane = t & 63;
    const int sub  = lane >> 4;
    const int c16  = lane & 15;
    const int seg  = bin * 8 + w;
    const int b    = seg >> 10;
    const f32x4* __restrict__ x1b = x14 + ((size_t)b << 10) * 16;
    const int cs = hist[w], bs = base2[w];
    int dtrue = cs;

    f32x4 acc = {0.f, 0.f, 0.f, 0.f};
    #pragma unroll 2
    for (int it = 0; it < cs; it += 4) {
        int idx = it + sub;
        const float m = (idx < cs) ? 1.f : 0.f;
        idx = min(idx, cs - 1);
        const int2 r = srt[bs + idx];
        const int e = r.x & 0xFFFFF;
        const int j = (r.y >> 10) & 1023, k = r.y & 1023;
        const f32x4 wv = __builtin_nontemporal_load(Wv4 + (size_t)e * 16 + c16);
        const f32x4 xj = x1b[j * 16 + c16];
        const f32x4 xk = x1b[k * 16 + c16];
        acc += (m * wv) * (xj * xk);
    }

    const int novf = min(ovf_cnt[0], OVF_MAX);
    if (novf > 0) {
        for (int o = 0; o < novf; ++o) {
            const int4 r = ovf[o];
            if (r.x == seg) {
                ++dtrue;
                const float m = (sub == 0) ? 1.f : 0.f;
                const int j = (r.z >> 10) & 1023, k = r.z & 1023;
                const f32x4 wv = Wv4[(size_t)(unsigned)r.y * 16 + c16];
                acc += (m * wv) * (x1b[j * 16 + c16] * x1b[k * 16 + c16]);
            }
        }
    }

    #pragma unroll
    for (int mm = 16; mm < 64; mm <<= 1) {
        acc.x += __shfl_xor(acc.x, mm);
        acc.y += __shfl_xor(acc.y, mm);
        acc.z += __shfl_xor(acc.z, mm);
        acc.w += __shfl_xor(acc.w, mm);
    }

    if (sub == 0) {
        const float a = 1.0f / ((float)dtrue + 1e-10f);
        f32x4 o = out4[(size_t)seg * 16 + c16];
        out4[(size_t)seg * 16 + c16] = o + a * acc;
    }
}

extern "C" void kernel_launch(void* const* d_in, const int* in_sizes, int n_in,
                              void* d_out, int out_size, void* d_ws, size_t ws_size,
                              hipStream_t stream) {
    const float* x   = (const float*)d_in[0];
    const float* Wv  = (const float*)d_in[1];
    const int*   eb  = (const int*)d_in[2];
    const int*   ei  = (const int*)d_in[3];
    const int*   ej  = (const int*)d_in[4];
    const int*   ek  = (const int*)d_in[5];
    const float* W1  = (const float*)d_in[6];
    const float* b1  = (const float*)d_in[7];
    const float* W2  = (const float*)d_in[8];
    const float* b2  = (const float*)d_in[9];
    const float* Ws1 = (const float*)d_in[10];
    const float* bs1 = (const float*)d_in[11];
    const float* Ws2 = (const float*)d_in[12];
    const float* bs2 = (const float*)d_in[13];
    float* out = (float*)d_out;
    const int nnz = in_sizes[2];

    char* ws = (char*)d_ws;
    float* x1    = (float*)ws;                              // [0, 2MB)
    float* x1s   = (float*)(ws + (2 << 20));                // shadow x1
    float* outs  = (float*)(ws + (4 << 20));                // shadow out (scratch)
    int* gcur    = (int*)(ws + (6 << 20));                  // NBIN ints
    int* ovf_cnt = gcur + NBIN;                             // 4 B
    int* gcur2   = gcur + NBIN + 1;                         // shadow cursors
    int* ovf_cnt2= gcur2 + NBIN;
    int4* ovf    = (int4*)(ws + (6 << 20) + (128 << 10));   // 64 KB
    int4* ovf2   = (int4*)(ws + (6 << 20) + (192 << 10));   // 64 KB
    int2* rec    = (int2*)(ws + (8 << 20));                 // 9.7 MB
    int2* rec2   = (int2*)(ws + (20 << 20));                // shadow rec

    const int nsb = (nnz + 8191) / 8192;   // 128 sort blocks
    const int nmlp = BN / 16;              // 512 MLP blocks

    (void)hipMemsetAsync(gcur, 0, (2 * NBIN + 2) * sizeof(int), stream);
    prep_kernel<<<nsb + nmlp, 1024, 0, stream>>>(x, W1, b1, W2, b2, Ws1, bs1, Ws2, bs2,
                                                 eb, ei, ej, ek, gcur, rec, ovf_cnt, ovf,
                                                 x1, out, nnz, nsb);
    // Instrumentation: identical shadow prep. Delta(dur_us) vs round 17 == T_prep.
    prep_kernel<<<nsb + nmlp, 1024, 0, stream>>>(x, W1, b1, W2, b2, Ws1, bs1, Ws2, bs2,
                                                 eb, ei, ej, ek, gcur2, rec2, ovf_cnt2, ovf2,
                                                 x1s, outs, nnz, nsb);
    gather_kernel<<<NBIN, 512, 0, stream>>>((const f32x4*)Wv, (const f32x4*)x1,
                                            gcur, rec, ovf_cnt, ovf, (f32x4*)out);
}

// Round 20
// 135.447 us; speedup vs baseline: 1.0924x; 1.0924x over previous
//
#include <hip/hip_runtime.h>

#define BN 8192      // B*N
#define NP 1024      // N
#define NF 64        // F_OUT
#define NSEG 8192
#define NBIN 1024    // bins of 8 segments (bin = seg >> 3)
#define CAPBIN 1184  // Poisson(1024) + 5 sigma; overflow exact
#define OVF_MAX 4096
#define OVFS (1 << 30)   // sentinel: cursor values >= OVFS index the ovf list

typedef float f32x4 __attribute__((ext_vector_type(4)));

// K1: blocks [0,nsb): block-local counting sort of 8192 edges into dense global
//     per-bin strips. blocks [nsb,..): dual MLP, 16 rows/block. (R17, unchanged.)
__global__ __launch_bounds__(1024) void prep_kernel(
    const float* __restrict__ x,
    const float* __restrict__ W1, const float* __restrict__ b1,
    const float* __restrict__ W2, const float* __restrict__ b2,
    const float* __restrict__ Ws1, const float* __restrict__ bs1,
    const float* __restrict__ Ws2, const float* __restrict__ bs2,
    const int* __restrict__ eb, const int* __restrict__ ei,
    const int* __restrict__ ej, const int* __restrict__ ek,
    int* __restrict__ gcur, int2* __restrict__ rec,
    int* __restrict__ ovf_cnt, int4* __restrict__ ovf,
    float* __restrict__ x1, float* __restrict__ out,
    int nnz, int nsb)
{
    if ((int)blockIdx.x < nsb) {
        __shared__ int hist[NBIN];
        __shared__ int cur[NBIN];
        const int t = threadIdx.x;
        hist[t] = 0;
        __syncthreads();

        int segs[8], jks[8];
        const int base = blockIdx.x * 8192;
        #pragma unroll
        for (int q = 0; q < 2; ++q) {
            const int e0 = base + (q * 1024 + t) * 4;
            if (e0 < nnz) {
                const int4 b4 = *(const int4*)(eb + e0);
                const int4 i4 = *(const int4*)(ei + e0);
                const int4 j4 = *(const int4*)(ej + e0);
                const int4 k4 = *(const int4*)(ek + e0);
                segs[q*4+0] = b4.x * NP + i4.x;  jks[q*4+0] = (j4.x << 10) | k4.x;
                segs[q*4+1] = b4.y * NP + i4.y;  jks[q*4+1] = (j4.y << 10) | k4.y;
                segs[q*4+2] = b4.z * NP + i4.z;  jks[q*4+2] = (j4.z << 10) | k4.z;
                segs[q*4+3] = b4.w * NP + i4.w;  jks[q*4+3] = (j4.w << 10) | k4.w;
                #pragma unroll
                for (int c = 0; c < 4; ++c)
                    atomicAdd(&hist[segs[q*4+c] >> 3], 1);
            } else {
                #pragma unroll
                for (int c = 0; c < 4; ++c) segs[q*4+c] = -1;
            }
        }
        __syncthreads();

        {
            const int v = hist[t];
            int c = 0;
            if (v > 0) {
                const int r = atomicAdd(&gcur[t], v);
                if (r + v <= CAPBIN) {
                    c = t * CAPBIN + r;
                } else {
                    atomicSub(&gcur[t], v);
                    c = OVFS + atomicAdd(ovf_cnt, v);
                }
            }
            cur[t] = c;
        }
        __syncthreads();

        #pragma unroll
        for (int q = 0; q < 2; ++q) {
            #pragma unroll
            for (int c = 0; c < 4; ++c) {
                const int idx = q * 4 + c;
                if (segs[idx] >= 0) {
                    const int e = base + (q * 1024 + t) * 4 + c;
                    const int seg = segs[idx];
                    const int p = atomicAdd(&cur[seg >> 3], 1);   // LDS atomic
                    if (p < OVFS) {
                        rec[p] = make_int2(e | ((seg & 7) << 20), jks[idx]);
                    } else {
                        const int o = p - OVFS;
                        if (o < OVF_MAX) ovf[o] = make_int4(seg, e, jks[idx], 0);
                    }
                }
            }
        }
    } else {
        const int row = ((int)blockIdx.x - nsb) * 16 + ((int)threadIdx.x >> 6);
        const int t = threadIdx.x & 63;
        const float xv = x[(size_t)row * NF + t];
        float a1 = b1[t], a2 = bs1[t];
        #pragma unroll 8
        for (int c = 0; c < NF; ++c) {
            const float xc = __shfl(xv, c);
            a1 = fmaf(xc, W1[c * NF + t], a1);
            a2 = fmaf(xc, Ws1[c * NF + t], a2);
        }
        const float h1 = fmaxf(a1, 0.f), h2 = fmaxf(a2, 0.f);
        float o1 = b2[t], o2 = bs2[t];
        #pragma unroll 8
        for (int c = 0; c < NF; ++c) {
            o1 = fmaf(__shfl(h1, c), W2[c * NF + t], o1);
            o2 = fmaf(__shfl(h2, c), Ws2[c * NF + t], o2);
        }
        x1[(size_t)row * NF + t]  = fmaxf(o1, 0.f);
        out[(size_t)row * NF + t] = fmaxf(o2, 0.f);
    }
}

// K2: block per bin (512 thr = 8 waves). NO seg-sort: walk the strip in chunk
// order (preserves per-chunk e-locality in the Wv stream) with 8 compile-time
// masked accumulators per lane; deg recovered by predicate counting.
// NOTE: after the sub-group shfl_xor reduce, each edge is counted exactly ONCE
// (the reduce sums the 4 subs at fixed c16, one lane per group) — no /16.
__global__ __launch_bounds__(512, 4) void gather_kernel(
    const f32x4* __restrict__ Wv4, const f32x4* __restrict__ x14,
    const int* __restrict__ gcur, const int2* __restrict__ rec,
    const int* __restrict__ ovf_cnt, const int4* __restrict__ ovf,
    f32x4* __restrict__ out4)
{
    __shared__ int2 srec[CAPBIN];
    __shared__ float part[8][8][NF];      // [wave][seg][feature], 16 KB
    __shared__ float dpart[8][8];
    const int bin = blockIdx.x;
    const int t = threadIdx.x;
    const int cnt = gcur[bin];

    const int2* strip = rec + (size_t)bin * CAPBIN;
    for (int i = t; i < cnt; i += 512)
        srec[i] = strip[i];
    __syncthreads();

    const int w    = t >> 6;
    const int lane = t & 63;
    const int sub  = lane >> 4;
    const int c16  = lane & 15;
    const int b    = bin >> 7;            // seg>>10 for all 8 segs of this bin
    const f32x4* __restrict__ x1b = x14 + ((size_t)b << 10) * 16;

    const int lo = (cnt * w) >> 3;
    const int hi = (cnt * (w + 1)) >> 3;

    f32x4 acc[8];
    float dc[8];
    #pragma unroll
    for (int s = 0; s < 8; ++s) { acc[s] = (f32x4){0.f,0.f,0.f,0.f}; dc[s] = 0.f; }

    for (int idx = lo + sub; idx < hi; idx += 4) {
        const int2 r = srec[idx];
        const int e  = r.x & 0xFFFFF;
        const int ws = (r.x >> 20) & 7;
        const int j = (r.y >> 10) & 1023, k = r.y & 1023;
        const f32x4 wv = __builtin_nontemporal_load(Wv4 + (size_t)e * 16 + c16);
        const f32x4 xj = x1b[j * 16 + c16];
        const f32x4 xk = x1b[k * 16 + c16];
        const f32x4 v = wv * (xj * xk);
        #pragma unroll
        for (int s = 0; s < 8; ++s) {
            const float p = (ws == s) ? 1.f : 0.f;
            acc[s] += p * v;
            dc[s]  += p;                  // once per edge after sub-reduce
        }
    }

    // exact overflow path (expected empty), wave 0 only
    const int novf = min(ovf_cnt[0], OVF_MAX);
    if (novf > 0 && w == 0) {
        for (int o = 0; o < novf; ++o) {
            const int4 r = ovf[o];
            const int s0 = r.x - bin * 8;
            if (s0 >= 0 && s0 < 8) {
                const float m = (sub == 0) ? 1.f : 0.f;
                const int j = (r.z >> 10) & 1023, k = r.z & 1023;
                const f32x4 wv = Wv4[(size_t)(unsigned)r.y * 16 + c16];
                const f32x4 v = (m * wv) * (x1b[j * 16 + c16] * x1b[k * 16 + c16]);
                #pragma unroll
                for (int s = 0; s < 8; ++s) {
                    const float p = (s0 == s) ? 1.f : 0.f;
                    acc[s] += p * v;
                    dc[s]  += p * 0.25f;  // 4 subs sum to exactly 1 per edge
                }
            }
        }
    }

    // combine the 4 sub-groups within each wave (lanes ^16, ^32)
    #pragma unroll
    for (int s = 0; s < 8; ++s) {
        #pragma unroll
        for (int mm = 16; mm < 64; mm <<= 1) {
            acc[s].x += __shfl_xor(acc[s].x, mm);
            acc[s].y += __shfl_xor(acc[s].y, mm);
            acc[s].z += __shfl_xor(acc[s].z, mm);
            acc[s].w += __shfl_xor(acc[s].w, mm);
            dc[s]    += __shfl_xor(dc[s], mm);
        }
    }
    if (sub == 0) {
        #pragma unroll
        for (int s = 0; s < 8; ++s)
            *(f32x4*)&part[w][s][c16 * 4] = acc[s];
    }
    if (lane == 0) {
        #pragma unroll
        for (int s = 0; s < 8; ++s) dpart[w][s] = dc[s];
    }
    __syncthreads();

    // final cross-wave reduce + normalize + RMW (128 threads)
    if (t < 128) {
        const int s = t >> 4, cc = t & 15;
        f32x4 sum = {0.f, 0.f, 0.f, 0.f};
        float d = 0.f;
        #pragma unroll
        for (int ww = 0; ww < 8; ++ww) {
            sum += *(const f32x4*)&part[ww][s][cc * 4];
            d += dpart[ww][s];
        }
        const int seg = bin * 8 + s;
        const float a = 1.0f / (d + 1e-10f);   // d == exact deg (no /16)
        f32x4 o = out4[(size_t)seg * 16 + cc];
        out4[(size_t)seg * 16 + cc] = o + a * sum;
    }
}

extern "C" void kernel_launch(void* const* d_in, const int* in_sizes, int n_in,
                              void* d_out, int out_size, void* d_ws, size_t ws_size,
                              hipStream_t stream) {
    const float* x   = (const float*)d_in[0];
    const float* Wv  = (const float*)d_in[1];
    const int*   eb  = (const int*)d_in[2];
    const int*   ei  = (const int*)d_in[3];
    const int*   ej  = (const int*)d_in[4];
    const int*   ek  = (const int*)d_in[5];
    const float* W1  = (const float*)d_in[6];
    const float* b1  = (const float*)d_in[7];
    const float* W2  = (const float*)d_in[8];
    const float* b2  = (const float*)d_in[9];
    const float* Ws1 = (const float*)d_in[10];
    const float* bs1 = (const float*)d_in[11];
    const float* Ws2 = (const float*)d_in[12];
    const float* bs2 = (const float*)d_in[13];
    float* out = (float*)d_out;
    const int nnz = in_sizes[2];

    char* ws = (char*)d_ws;
    float* x1    = (float*)ws;                             // [0, 2MB)
    int* gcur    = (int*)(ws + (2 << 20));                 // NBIN ints
    int* ovf_cnt = gcur + NBIN;                            // 4 B
    int4* ovf    = (int4*)(ws + (2 << 20) + (64 << 10));   // 64 KB
    int2* rec    = (int2*)(ws + (4 << 20));                // 9.7 MB

    const int nsb = (nnz + 8191) / 8192;   // 128 sort blocks
    const int nmlp = BN / 16;              // 512 MLP blocks

    (void)hipMemsetAsync(gcur, 0, (NBIN + 1) * sizeof(int), stream);
    prep_kernel<<<nsb + nmlp, 1024, 0, stream>>>(x, W1, b1, W2, b2, Ws1, bs1, Ws2, bs2,
                                                 eb, ei, ej, ek, gcur, rec, ovf_cnt, ovf,
                                                 x1, out, nnz, nsb);
    gather_kernel<<<NBIN, 512, 0, stream>>>((const f32x4*)Wv, (const f32x4*)x1,
                                            gcur, rec, ovf_cnt, ovf, (f32x4*)out);
}

// Round 21
// 118.299 us; speedup vs baseline: 1.2508x; 1.1450x over previous
//
#include <hip/hip_runtime.h>

#define BN 8192      // B*N
#define NP 1024      // N
#define NF 64        // F_OUT
#define NSEG 8192
#define NBIN 1024    // bins of 8 segments (bin = seg >> 3)
#define CAPBIN 1184  // Poisson(1024) + 5 sigma; overflow exact
#define EPB 4096     // edges per sort block (4 per thread)
#define OVF_MAX 4096
#define OVFS (1 << 30)   // sentinel: cursor values >= OVFS index the ovf list

typedef float f32x4 __attribute__((ext_vector_type(4)));

// K1: blocks [0,nsb): block-local counting sort of 4096 edges into dense global
//     per-bin strips. blocks [nsb,..): dual MLP, 16 rows/block.
__global__ __launch_bounds__(1024) void prep_kernel(
    const float* __restrict__ x,
    const float* __restrict__ W1, const float* __restrict__ b1,
    const float* __restrict__ W2, const float* __restrict__ b2,
    const float* __restrict__ Ws1, const float* __restrict__ bs1,
    const float* __restrict__ Ws2, const float* __restrict__ bs2,
    const int* __restrict__ eb, const int* __restrict__ ei,
    const int* __restrict__ ej, const int* __restrict__ ek,
    int* __restrict__ gcur, int2* __restrict__ rec,
    int* __restrict__ ovf_cnt, int4* __restrict__ ovf,
    float* __restrict__ x1, float* __restrict__ out,
    int nnz, int nsb)
{
    if ((int)blockIdx.x < nsb) {
        __shared__ int hist[NBIN];
        __shared__ int cur[NBIN];
        const int t = threadIdx.x;
        hist[t] = 0;
        __syncthreads();

        int segs[4], jks[4];
        const int e0 = blockIdx.x * EPB + t * 4;
        if (e0 < nnz) {
            const int4 b4 = *(const int4*)(eb + e0);
            const int4 i4 = *(const int4*)(ei + e0);
            const int4 j4 = *(const int4*)(ej + e0);
            const int4 k4 = *(const int4*)(ek + e0);
            segs[0] = b4.x * NP + i4.x;  jks[0] = (j4.x << 10) | k4.x;
            segs[1] = b4.y * NP + i4.y;  jks[1] = (j4.y << 10) | k4.y;
            segs[2] = b4.z * NP + i4.z;  jks[2] = (j4.z << 10) | k4.z;
            segs[3] = b4.w * NP + i4.w;  jks[3] = (j4.w << 10) | k4.w;
            #pragma unroll
            for (int c = 0; c < 4; ++c)
                atomicAdd(&hist[segs[c] >> 3], 1);
        } else {
            #pragma unroll
            for (int c = 0; c < 4; ++c) segs[c] = -1;
        }
        __syncthreads();

        {
            const int v = hist[t];
            int c = 0;
            if (v > 0) {
                const int r = atomicAdd(&gcur[t], v);
                if (r + v <= CAPBIN) {
                    c = t * CAPBIN + r;
                } else {
                    atomicSub(&gcur[t], v);
                    c = OVFS + atomicAdd(ovf_cnt, v);
                }
            }
            cur[t] = c;
        }
        __syncthreads();

        #pragma unroll
        for (int c = 0; c < 4; ++c) {
            if (segs[c] >= 0) {
                const int e = e0 + c;
                const int seg = segs[c];
                const int p = atomicAdd(&cur[seg >> 3], 1);   // LDS atomic
                if (p < OVFS) {
                    rec[p] = make_int2(e | ((seg & 7) << 20), jks[c]);
                } else {
                    const int o = p - OVFS;
                    if (o < OVF_MAX) ovf[o] = make_int4(seg, e, jks[c], 0);
                }
            }
        }
    } else {
        const int row = ((int)blockIdx.x - nsb) * 16 + ((int)threadIdx.x >> 6);
        const int t = threadIdx.x & 63;
        const float xv = x[(size_t)row * NF + t];
        float a1 = b1[t], a2 = bs1[t];
        #pragma unroll 8
        for (int c = 0; c < NF; ++c) {
            const float xc = __shfl(xv, c);
            a1 = fmaf(xc, W1[c * NF + t], a1);
            a2 = fmaf(xc, Ws1[c * NF + t], a2);
        }
        const float h1 = fmaxf(a1, 0.f), h2 = fmaxf(a2, 0.f);
        float o1 = b2[t], o2 = bs2[t];
        #pragma unroll 8
        for (int c = 0; c < NF; ++c) {
            o1 = fmaf(__shfl(h1, c), W2[c * NF + t], o1);
            o2 = fmaf(__shfl(h2, c), Ws2[c * NF + t], o2);
        }
        x1[(size_t)row * NF + t]  = fmaxf(o1, 0.f);
        out[(size_t)row * NF + t] = fmaxf(o2, 0.f);
    }
}

// K2: block per bin (512 thr = 8 waves). Byte-identical to round 17.
__global__ __launch_bounds__(512, 8) void gather_kernel(
    const f32x4* __restrict__ Wv4, const f32x4* __restrict__ x14,
    const int* __restrict__ gcur, const int2* __restrict__ rec,
    const int* __restrict__ ovf_cnt, const int4* __restrict__ ovf,
    f32x4* __restrict__ out4)
{
    __shared__ int2 srt[CAPBIN];
    __shared__ int hist[8], cur2[8], base2[8];
    const int bin = blockIdx.x;
    const int t = threadIdx.x;
    const int cnt = gcur[bin];
    if (t < 8) hist[t] = 0;
    __syncthreads();

    const int2* strip = rec + (size_t)bin * CAPBIN;
    #pragma unroll
    for (int i = 0; i < 3; ++i) {
        const int idx = i * 512 + t;
        if (idx < cnt) atomicAdd(&hist[(strip[idx].x >> 20) & 7], 1);
    }
    __syncthreads();
    if (t < 8) {
        int bsum = 0;
        for (int s = 0; s < t; ++s) bsum += hist[s];
        base2[t] = bsum; cur2[t] = bsum;
    }
    __syncthreads();
    #pragma unroll
    for (int i = 0; i < 3; ++i) {
        const int idx = i * 512 + t;
        if (idx < cnt) {
            const int2 r = strip[idx];
            srt[atomicAdd(&cur2[(r.x >> 20) & 7], 1)] = r;
        }
    }
    __syncthreads();

    const int w    = t >> 6;
    const int lane = t & 63;
    const int sub  = lane >> 4;
    const int c16  = lane & 15;
    const int seg  = bin * 8 + w;
    const int b    = seg >> 10;
    const f32x4* __restrict__ x1b = x14 + ((size_t)b << 10) * 16;
    const int cs = hist[w], bs = base2[w];
    int dtrue = cs;

    f32x4 acc = {0.f, 0.f, 0.f, 0.f};
    #pragma unroll 2
    for (int it = 0; it < cs; it += 4) {
        int idx = it + sub;
        const float m = (idx < cs) ? 1.f : 0.f;
        idx = min(idx, cs - 1);
        const int2 r = srt[bs + idx];
        const int e = r.x & 0xFFFFF;
        const int j = (r.y >> 10) & 1023, k = r.y & 1023;
        const f32x4 wv = __builtin_nontemporal_load(Wv4 + (size_t)e * 16 + c16);
        const f32x4 xj = x1b[j * 16 + c16];
        const f32x4 xk = x1b[k * 16 + c16];
        acc += (m * wv) * (xj * xk);
    }

    const int novf = min(ovf_cnt[0], OVF_MAX);
    if (novf > 0) {
        for (int o = 0; o < novf; ++o) {
            const int4 r = ovf[o];
            if (r.x == seg) {
                ++dtrue;
                const float m = (sub == 0) ? 1.f : 0.f;
                const int j = (r.z >> 10) & 1023, k = r.z & 1023;
                const f32x4 wv = Wv4[(size_t)(unsigned)r.y * 16 + c16];
                acc += (m * wv) * (x1b[j * 16 + c16] * x1b[k * 16 + c16]);
            }
        }
    }

    #pragma unroll
    for (int mm = 16; mm < 64; mm <<= 1) {
        acc.x += __shfl_xor(acc.x, mm);
        acc.y += __shfl_xor(acc.y, mm);
        acc.z += __shfl_xor(acc.z, mm);
        acc.w += __shfl_xor(acc.w, mm);
    }

    if (sub == 0) {
        const float a = 1.0f / ((float)dtrue + 1e-10f);
        f32x4 o = out4[(size_t)seg * 16 + c16];
        out4[(size_t)seg * 16 + c16] = o + a * acc;
    }
}

extern "C" void kernel_launch(void* const* d_in, const int* in_sizes, int n_in,
                              void* d_out, int out_size, void* d_ws, size_t ws_size,
                              hipStream_t stream) {
    const float* x   = (const float*)d_in[0];
    const float* Wv  = (const float*)d_in[1];
    const int*   eb  = (const int*)d_in[2];
    const int*   ei  = (const int*)d_in[3];
    const int*   ej  = (const int*)d_in[4];
    const int*   ek  = (const int*)d_in[5];
    const float* W1  = (const float*)d_in[6];
    const float* b1  = (const float*)d_in[7];
    const float* W2  = (const float*)d_in[8];
    const float* b2  = (const float*)d_in[9];
    const float* Ws1 = (const float*)d_in[10];
    const float* bs1 = (const float*)d_in[11];
    const float* Ws2 = (const float*)d_in[12];
    const float* bs2 = (const float*)d_in[13];
    float* out = (float*)d_out;
    const int nnz = in_sizes[2];

    char* ws = (char*)d_ws;
    float* x1    = (float*)ws;                             // [0, 2MB)
    int* gcur    = (int*)(ws + (2 << 20));                 // NBIN ints
    int* ovf_cnt = gcur + NBIN;                            // 4 B
    int4* ovf    = (int4*)(ws + (2 << 20) + (64 << 10));   // 64 KB
    int2* rec    = (int2*)(ws + (4 << 20));                // 9.7 MB

    const int nsb = (nnz + EPB - 1) / EPB;   // 256 sort blocks (1024 thr x 4 edges)
    const int nmlp = BN / 16;                // 512 MLP blocks (16 waves x 1 row)

    (void)hipMemsetAsync(gcur, 0, (NBIN + 1) * sizeof(int), stream);
    prep_kernel<<<nsb + nmlp, 1024, 0, stream>>>(x, W1, b1, W2, b2, Ws1, bs1, Ws2, bs2,
                                                 eb, ei, ej, ek, gcur, rec, ovf_cnt, ovf,
                                                 x1, out, nnz, nsb);
    gather_kernel<<<NBIN, 512, 0, stream>>>((const f32x4*)Wv, (const f32x4*)x1,
                                            gcur, rec, ovf_cnt, ovf, (f32x4*)out);
}

// Round 22
// 113.863 us; speedup vs baseline: 1.2995x; 1.0390x over previous
//
#include <hip/hip_runtime.h>

#define BN 8192      // B*N
#define NP 1024      // N
#define NF 64        // F_OUT
#define NSEG 8192
#define NBIN 1024    // bins of 8 segments (bin = seg >> 3)
#define CAPBIN 1184  // Poisson(1024) + 5 sigma; overflow exact
#define OVF_MAX 4096
#define OVFS (1 << 30)   // sentinel: cursor values >= OVFS index the ovf list

typedef float f32x4 __attribute__((ext_vector_type(4)));

// K1: blocks [0,nsb): block-local counting sort of 8192 edges into dense global
//     per-bin strips (R17 structure). blocks [nsb,..): x1-MLP only, 16 rows/block.
__global__ __launch_bounds__(1024) void prep_kernel(
    const float* __restrict__ x,
    const float* __restrict__ W1, const float* __restrict__ b1,
    const float* __restrict__ W2, const float* __restrict__ b2,
    const int* __restrict__ eb, const int* __restrict__ ei,
    const int* __restrict__ ej, const int* __restrict__ ek,
    int* __restrict__ gcur, int2* __restrict__ rec,
    int* __restrict__ ovf_cnt, int4* __restrict__ ovf,
    float* __restrict__ x1,
    int nnz, int nsb)
{
    if ((int)blockIdx.x < nsb) {
        __shared__ int hist[NBIN];
        __shared__ int cur[NBIN];
        const int t = threadIdx.x;
        hist[t] = 0;
        __syncthreads();

        int segs[8], jks[8];
        const int base = blockIdx.x * 8192;
        #pragma unroll
        for (int q = 0; q < 2; ++q) {
            const int e0 = base + (q * 1024 + t) * 4;
            if (e0 < nnz) {
                const int4 b4 = *(const int4*)(eb + e0);
                const int4 i4 = *(const int4*)(ei + e0);
                const int4 j4 = *(const int4*)(ej + e0);
                const int4 k4 = *(const int4*)(ek + e0);
                segs[q*4+0] = b4.x * NP + i4.x;  jks[q*4+0] = (j4.x << 10) | k4.x;
                segs[q*4+1] = b4.y * NP + i4.y;  jks[q*4+1] = (j4.y << 10) | k4.y;
                segs[q*4+2] = b4.z * NP + i4.z;  jks[q*4+2] = (j4.z << 10) | k4.z;
                segs[q*4+3] = b4.w * NP + i4.w;  jks[q*4+3] = (j4.w << 10) | k4.w;
                #pragma unroll
                for (int c = 0; c < 4; ++c)
                    atomicAdd(&hist[segs[q*4+c] >> 3], 1);
            } else {
                #pragma unroll
                for (int c = 0; c < 4; ++c) segs[q*4+c] = -1;
            }
        }
        __syncthreads();

        {
            const int v = hist[t];
            int c = 0;
            if (v > 0) {
                const int r = atomicAdd(&gcur[t], v);
                if (r + v <= CAPBIN) {
                    c = t * CAPBIN + r;
                } else {
                    atomicSub(&gcur[t], v);
                    c = OVFS + atomicAdd(ovf_cnt, v);
                }
            }
            cur[t] = c;
        }
        __syncthreads();

        #pragma unroll
        for (int q = 0; q < 2; ++q) {
            #pragma unroll
            for (int c = 0; c < 4; ++c) {
                const int idx = q * 4 + c;
                if (segs[idx] >= 0) {
                    const int e = base + (q * 1024 + t) * 4 + c;
                    const int seg = segs[idx];
                    const int p = atomicAdd(&cur[seg >> 3], 1);   // LDS atomic
                    if (p < OVFS) {
                        rec[p] = make_int2(e | ((seg & 7) << 20), jks[idx]);
                    } else {
                        const int o = p - OVFS;
                        if (o < OVF_MAX) ovf[o] = make_int4(seg, e, jks[idx], 0);
                    }
                }
            }
        }
    } else {
        // x1-MLP only (self-MLP moved into gather): one wave per row
        const int row = ((int)blockIdx.x - nsb) * 16 + ((int)threadIdx.x >> 6);
        const int t = threadIdx.x & 63;
        const float xv = x[(size_t)row * NF + t];
        float a1 = b1[t];
        #pragma unroll 8
        for (int c = 0; c < NF; ++c)
            a1 = fmaf(__shfl(xv, c), W1[c * NF + t], a1);
        const float h1 = fmaxf(a1, 0.f);
        float o1 = b2[t];
        #pragma unroll 8
        for (int c = 0; c < NF; ++c)
            o1 = fmaf(__shfl(h1, c), W2[c * NF + t], o1);
        x1[(size_t)row * NF + t] = fmaxf(o1, 0.f);
    }
}

// K2: block per bin (512 thr = 8 waves). R17 gather + self-MLP epilogue:
// wave w computes the self-MLP for its seg (shfl bcast, weights L2-hot), and
// the final write is a pure store (no out read).
__global__ __launch_bounds__(512, 8) void gather_kernel(
    const f32x4* __restrict__ Wv4, const f32x4* __restrict__ x14,
    const float* __restrict__ x,
    const float* __restrict__ Ws1, const float* __restrict__ bs1,
    const float* __restrict__ Ws2, const float* __restrict__ bs2,
    const int* __restrict__ gcur, const int2* __restrict__ rec,
    const int* __restrict__ ovf_cnt, const int4* __restrict__ ovf,
    f32x4* __restrict__ out4)
{
    __shared__ int2 srt[CAPBIN];
    __shared__ float smlp[8][NF];
    __shared__ int hist[8], cur2[8], base2[8];
    const int bin = blockIdx.x;
    const int t = threadIdx.x;
    const int w    = t >> 6;
    const int lane = t & 63;
    const int cnt = gcur[bin];
    if (t < 8) hist[t] = 0;

    // self-MLP for seg = bin*8 + w (independent of the sort; issues early)
    {
        const int seg = bin * 8 + w;
        const float xv = x[(size_t)seg * NF + lane];
        float a2 = bs1[lane];
        #pragma unroll 8
        for (int c = 0; c < NF; ++c)
            a2 = fmaf(__shfl(xv, c), Ws1[c * NF + lane], a2);
        const float h2 = fmaxf(a2, 0.f);
        float o2 = bs2[lane];
        #pragma unroll 8
        for (int c = 0; c < NF; ++c)
            o2 = fmaf(__shfl(h2, c), Ws2[c * NF + lane], o2);
        smlp[w][lane] = fmaxf(o2, 0.f);
    }
    __syncthreads();

    const int2* strip = rec + (size_t)bin * CAPBIN;
    #pragma unroll
    for (int i = 0; i < 3; ++i) {                  // 3*512 >= CAPBIN
        const int idx = i * 512 + t;
        if (idx < cnt) atomicAdd(&hist[(strip[idx].x >> 20) & 7], 1);
    }
    __syncthreads();
    if (t < 8) {
        int bsum = 0;
        for (int s = 0; s < t; ++s) bsum += hist[s];
        base2[t] = bsum; cur2[t] = bsum;
    }
    __syncthreads();
    #pragma unroll
    for (int i = 0; i < 3; ++i) {                  // L2-hot second pass
        const int idx = i * 512 + t;
        if (idx < cnt) {
            const int2 r = strip[idx];
            srt[atomicAdd(&cur2[(r.x >> 20) & 7], 1)] = r;
        }
    }
    __syncthreads();

    const int sub  = lane >> 4;
    const int c16  = lane & 15;
    const int seg  = bin * 8 + w;
    const int b    = seg >> 10;
    const f32x4* __restrict__ x1b = x14 + ((size_t)b << 10) * 16;
    const int cs = hist[w], bs = base2[w];
    int dtrue = cs;

    f32x4 acc = {0.f, 0.f, 0.f, 0.f};
    #pragma unroll 2
    for (int it = 0; it < cs; it += 4) {
        int idx = it + sub;
        const float m = (idx < cs) ? 1.f : 0.f;
        idx = min(idx, cs - 1);                     // cs >= 1 inside loop
        const int2 r = srt[bs + idx];
        const int e = r.x & 0xFFFFF;
        const int j = (r.y >> 10) & 1023, k = r.y & 1023;
        const f32x4 wv = __builtin_nontemporal_load(Wv4 + (size_t)e * 16 + c16);
        const f32x4 xj = x1b[j * 16 + c16];
        const f32x4 xk = x1b[k * 16 + c16];
        acc += (m * wv) * (xj * xk);
    }

    // exact overflow path (expected empty)
    const int novf = min(ovf_cnt[0], OVF_MAX);
    if (novf > 0) {
        for (int o = 0; o < novf; ++o) {
            const int4 r = ovf[o];
            if (r.x == seg) {
                ++dtrue;
                const float m = (sub == 0) ? 1.f : 0.f;
                const int j = (r.z >> 10) & 1023, k = r.z & 1023;
                const f32x4 wv = Wv4[(size_t)(unsigned)r.y * 16 + c16];
                acc += (m * wv) * (x1b[j * 16 + c16] * x1b[k * 16 + c16]);
            }
        }
    }

    #pragma unroll
    for (int mm = 16; mm < 64; mm <<= 1) {
        acc.x += __shfl_xor(acc.x, mm);
        acc.y += __shfl_xor(acc.y, mm);
        acc.z += __shfl_xor(acc.z, mm);
        acc.w += __shfl_xor(acc.w, mm);
    }

    if (sub == 0) {
        const float a = 1.0f / ((float)dtrue + 1e-10f);
        const f32x4 mv = *(const f32x4*)&smlp[w][c16 * 4];
        out4[(size_t)seg * 16 + c16] = mv + a * acc;   // pure store, no RMW
    }
}

extern "C" void kernel_launch(void* const* d_in, const int* in_sizes, int n_in,
                              void* d_out, int out_size, void* d_ws, size_t ws_size,
                              hipStream_t stream) {
    const float* x   = (const float*)d_in[0];
    const float* Wv  = (const float*)d_in[1];
    const int*   eb  = (const int*)d_in[2];
    const int*   ei  = (const int*)d_in[3];
    const int*   ej  = (const int*)d_in[4];
    const int*   ek  = (const int*)d_in[5];
    const float* W1  = (const float*)d_in[6];
    const float* b1  = (const float*)d_in[7];
    const float* W2  = (const float*)d_in[8];
    const float* b2  = (const float*)d_in[9];
    const float* Ws1 = (const float*)d_in[10];
    const float* bs1 = (const float*)d_in[11];
    const float* Ws2 = (const float*)d_in[12];
    const float* bs2 = (const float*)d_in[13];
    float* out = (float*)d_out;
    const int nnz = in_sizes[2];

    char* ws = (char*)d_ws;
    float* x1    = (float*)ws;                             // [0, 2MB)
    int* gcur    = (int*)(ws + (2 << 20));                 // NBIN ints
    int* ovf_cnt = gcur + NBIN;                            // 4 B
    int4* ovf    = (int4*)(ws + (2 << 20) + (64 << 10));   // 64 KB
    int2* rec    = (int2*)(ws + (4 << 20));                // 9.7 MB

    const int nsb = (nnz + 8191) / 8192;   // 128 sort blocks (1024 thr x 8 edges)
    const int nmlp = BN / 16;              // 512 MLP blocks (16 waves x 1 row)

    (void)hipMemsetAsync(gcur, 0, (NBIN + 1) * sizeof(int), stream);
    prep_kernel<<<nsb + nmlp, 1024, 0, stream>>>(x, W1, b1, W2, b2,
                                                 eb, ei, ej, ek, gcur, rec, ovf_cnt, ovf,
                                                 x1, nnz, nsb);
    gather_kernel<<<NBIN, 512, 0, stream>>>((const f32x4*)Wv, (const f32x4*)x1,
                                            x, Ws1, bs1, Ws2, bs2,
                                            gcur, rec, ovf_cnt, ovf, (f32x4*)out);
}